// Round 1
// baseline (1298.105 us; speedup 1.0000x reference)
//
#include <hip/hip_runtime.h>
#include <hip/hip_bf16.h>

#define NTOK 16384
#define CCH 128
#define O3 384
#define SQRT_C 11.313708498984761f
#define QSCALE 0.17677669529663687f

// ---------------- K0: transpose w_qkv [384][128] -> wT [128][384] ----------------
__global__ void k0_transpose(const float* __restrict__ wq, float* __restrict__ wT) {
    int i = blockIdx.x * 256 + threadIdx.x;   // i < 49152
    int o = i >> 7, c = i & 127;
    wT[c * O3 + o] = wq[i];
}

// ---------------- K1: rmsnorm + qkv + q-softmax + exp(k) context partials -------
// grid 512 = 16 batches x 32 chunks of 512 tokens; 256 threads; 16 subtiles of 32 tokens
__global__ void k1_qkv(const float* __restrict__ x, const float* __restrict__ g1,
                       const float* __restrict__ wT, __hip_bfloat16* __restrict__ qs,
                       float* __restrict__ pS, float* __restrict__ pC) {
    __shared__ float xq[O3][33];        // union: x subtile (rows 0..127) then qkv subtile
    __shared__ float accC[4][32][33];   // per-block context partial  [h][d][e(+pad)]
    __shared__ float accS[128];         // per-block exp-sum partial  [h*32+d]
    __shared__ float scaleS[32];
    __shared__ float g1s[CCH];
    __shared__ float nrm[8][32];

    const int tid = threadIdx.x;
    const int b = blockIdx.x >> 5;
    const int chunk = blockIdx.x & 31;
    const int t0 = chunk << 9;          // * 512

    for (int i = tid; i < 4 * 32 * 33; i += 256) ((float*)accC)[i] = 0.f;
    if (tid < 128) { accS[tid] = 0.f; g1s[tid] = g1[tid]; }

    const int og = tid >> 3, tg = tid & 7;
    const int o0 = og * 12, j0 = tg * 4;

    for (int st = 0; st < 16; ++st) {
        const int tb = t0 + st * 32;
        __syncthreads();                // protect xq/accC reads of previous iter
        // load x subtile [128][32], coalesced
        for (int i = tid; i < CCH * 32; i += 256) {
            int c = i >> 5, j = i & 31;
            xq[c][j] = x[(size_t)(b * CCH + c) * NTOK + tb + j];
        }
        __syncthreads();
        // channel-norm per token
        {
            int tt = tid & 31, qq = tid >> 5;
            float s = 0.f;
            #pragma unroll
            for (int c = 0; c < 16; ++c) { float v = xq[qq * 16 + c][tt]; s += v * v; }
            nrm[qq][tt] = s;
        }
        __syncthreads();
        if (tid < 32) {
            float s = 0.f;
            #pragma unroll
            for (int q = 0; q < 8; ++q) s += nrm[q][tid];
            scaleS[tid] = SQRT_C / fmaxf(sqrtf(s), 1e-12f);
        }
        __syncthreads();
        // xn = x * scale * g1 (in place)
        for (int i = tid; i < CCH * 32; i += 256) {
            int c = i >> 5, j = i & 31;
            xq[c][j] *= scaleS[j] * g1s[c];
        }
        __syncthreads();
        // GEMM: 384x32 output subtile; thread tile 12 outputs x 4 tokens
        float acc[12][4];
        #pragma unroll
        for (int a = 0; a < 12; ++a)
            #pragma unroll
            for (int jj = 0; jj < 4; ++jj) acc[a][jj] = 0.f;
        #pragma unroll 2
        for (int c = 0; c < CCH; ++c) {
            const float4* wrow = (const float4*)(wT + c * O3);
            float4 w4a = wrow[og * 3 + 0];
            float4 w4b = wrow[og * 3 + 1];
            float4 w4c = wrow[og * 3 + 2];
            float xv[4];
            #pragma unroll
            for (int jj = 0; jj < 4; ++jj) xv[jj] = xq[c][j0 + jj];
            #pragma unroll
            for (int jj = 0; jj < 4; ++jj) {
                acc[0][jj]  += w4a.x * xv[jj];
                acc[1][jj]  += w4a.y * xv[jj];
                acc[2][jj]  += w4a.z * xv[jj];
                acc[3][jj]  += w4a.w * xv[jj];
                acc[4][jj]  += w4b.x * xv[jj];
                acc[5][jj]  += w4b.y * xv[jj];
                acc[6][jj]  += w4b.z * xv[jj];
                acc[7][jj]  += w4b.w * xv[jj];
                acc[8][jj]  += w4c.x * xv[jj];
                acc[9][jj]  += w4c.y * xv[jj];
                acc[10][jj] += w4c.z * xv[jj];
                acc[11][jj] += w4c.w * xv[jj];
            }
        }
        __syncthreads();                // all x reads done; xq becomes qkv buffer
        #pragma unroll
        for (int a = 0; a < 12; ++a)
            #pragma unroll
            for (int jj = 0; jj < 4; ++jj) xq[o0 + a][j0 + jj] = acc[a][jj];
        __syncthreads();
        // q-softmax over head-dim (rows 0..127), in place, * 1/sqrt(32)
        if (tid < 128) {
            int tt = tid & 31, h = tid >> 5;
            float qv[32], m = -1e30f;
            #pragma unroll
            for (int d = 0; d < 32; ++d) { qv[d] = xq[h * 32 + d][tt]; m = fmaxf(m, qv[d]); }
            float s = 0.f;
            #pragma unroll
            for (int d = 0; d < 32; ++d) { qv[d] = __expf(qv[d] - m); s += qv[d]; }
            float inv = QSCALE / s;
            #pragma unroll
            for (int d = 0; d < 32; ++d) xq[h * 32 + d][tt] = qv[d] * inv;
        }
        // exp(k) in place (rows 128..255); disjoint rows, no sync needed vs q-softmax
        for (int i = tid; i < CCH * 32; i += 256) {
            int c = i >> 5, j = i & 31;
            xq[CCH + c][j] = __expf(xq[CCH + c][j]);
        }
        __syncthreads();
        // store q_soft as bf16, coalesced
        for (int i = tid; i < CCH * 32; i += 256) {
            int c = i >> 5, j = i & 31;
            qs[(size_t)(b * CCH + c) * NTOK + tb + j] = __float2bfloat16(xq[c][j]);
        }
        // accumulate exp-sum per (h,d)
        if (tid < 128) {
            float s = 0.f;
            #pragma unroll
            for (int j = 0; j < 32; ++j) s += xq[CCH + tid][j];
            accS[tid] += s;
        }
        // accumulate context partial: thread owns (h, d, 16 e's)
        {
            int h = tid >> 6, d = (tid >> 1) & 31, ep = tid & 1;
            float a16[16];
            #pragma unroll
            for (int e = 0; e < 16; ++e) a16[e] = 0.f;
            for (int j = 0; j < 32; ++j) {
                float ek = xq[CCH + h * 32 + d][j];
                #pragma unroll
                for (int e = 0; e < 16; ++e)
                    a16[e] += ek * xq[256 + h * 32 + ep * 16 + e][j];
            }
            #pragma unroll
            for (int e = 0; e < 16; ++e) accC[h][d][ep * 16 + e] += a16[e];
        }
    }
    __syncthreads();
    if (tid < 128) pS[(size_t)(b * 32 + chunk) * 128 + tid] = accS[tid];
    for (int i = tid; i < 4096; i += 256) {
        int h = i >> 10, d = (i >> 5) & 31, e = i & 31;
        pC[(size_t)(b * 32 + chunk) * 4096 + i] = accC[h][d][e];
    }
}

// ---------------- K2: reduce partials -> context -> M = Wout_h * ctx^T ----------
// grid 64 = (b,h); Mg layout [b][c'=h*32+d][o]
__global__ void k2_ctx(const float* __restrict__ pS, const float* __restrict__ pC,
                       const float* __restrict__ wout, float* __restrict__ Mg) {
    __shared__ float ctx[32][33];
    __shared__ float Sv[32];
    const int tid = threadIdx.x;
    const int b = blockIdx.x >> 2, h = blockIdx.x & 3;
    if (tid < 32) {
        float s = 0.f;
        for (int ch = 0; ch < 32; ++ch) s += pS[(size_t)(b * 32 + ch) * 128 + h * 32 + tid];
        Sv[tid] = s;
    }
    #pragma unroll
    for (int k = 0; k < 4; ++k) {
        int de = tid + k * 256;
        float s = 0.f;
        for (int ch = 0; ch < 32; ++ch) s += pC[(size_t)(b * 32 + ch) * 4096 + h * 1024 + de];
        ctx[de >> 5][de & 31] = s;
    }
    __syncthreads();
    #pragma unroll
    for (int k = 0; k < 4; ++k) {
        int de = tid + k * 256;
        ctx[de >> 5][de & 31] /= Sv[de >> 5];
    }
    __syncthreads();
    #pragma unroll
    for (int k = 0; k < 16; ++k) {
        int idx = tid + k * 256;
        int d = idx >> 7, o = idx & 127;
        float m = 0.f;
        #pragma unroll
        for (int e = 0; e < 32; ++e) m += wout[o * 128 + h * 32 + e] * ctx[d][e];
        Mg[(size_t)(b * 128 + h * 32 + d) * 128 + o] = m;
    }
}

// ---------------- K3: y = M_b @ q_soft + b_out, then rmsnorm(g2) ----------------
// grid 4096 = 16 batches x 256 chunks of 64 tokens
__global__ void k3_out(const __hip_bfloat16* __restrict__ qs, const float* __restrict__ Mg,
                       const float* __restrict__ bo, const float* __restrict__ g2,
                       float* __restrict__ out) {
    __shared__ float qt[CCH][65];       // union: q tile then y tile
    __shared__ float nrm[4][64];
    __shared__ float sc2[64];
    __shared__ float g2s[CCH], bos[CCH];
    const int tid = threadIdx.x;
    const int b = blockIdx.x >> 8;
    const int t0 = (blockIdx.x & 255) << 6;
    if (tid < 128) { g2s[tid] = g2[tid]; bos[tid] = bo[tid]; }
    for (int i = tid; i < CCH * 64; i += 256) {
        int c = i >> 6, j = i & 63;
        qt[c][j] = __bfloat162float(qs[(size_t)(b * CCH + c) * NTOK + t0 + j]);
    }
    __syncthreads();
    const int og = tid >> 3, tg = tid & 7;
    const int o0 = og * 4, j0 = tg * 8;
    float acc[4][8];
    #pragma unroll
    for (int a = 0; a < 4; ++a)
        #pragma unroll
        for (int jj = 0; jj < 8; ++jj) acc[a][jj] = 0.f;
    #pragma unroll 2
    for (int cp = 0; cp < CCH; ++cp) {
        float4 m4 = *(const float4*)(Mg + (size_t)(b * CCH + cp) * CCH + o0);
        float qv[8];
        #pragma unroll
        for (int jj = 0; jj < 8; ++jj) qv[jj] = qt[cp][j0 + jj];
        #pragma unroll
        for (int jj = 0; jj < 8; ++jj) {
            acc[0][jj] += m4.x * qv[jj];
            acc[1][jj] += m4.y * qv[jj];
            acc[2][jj] += m4.z * qv[jj];
            acc[3][jj] += m4.w * qv[jj];
        }
    }
    __syncthreads();                    // q reads done; reuse qt for y
    #pragma unroll
    for (int a = 0; a < 4; ++a)
        #pragma unroll
        for (int jj = 0; jj < 8; ++jj) qt[o0 + a][j0 + jj] = acc[a][jj] + bos[o0 + a];
    __syncthreads();
    {
        int tt = tid & 63, qq = tid >> 6;
        float s = 0.f;
        #pragma unroll
        for (int c = 0; c < 32; ++c) { float v = qt[qq * 32 + c][tt]; s += v * v; }
        nrm[qq][tt] = s;
    }
    __syncthreads();
    if (tid < 64) {
        float s = nrm[0][tid] + nrm[1][tid] + nrm[2][tid] + nrm[3][tid];
        sc2[tid] = SQRT_C / fmaxf(sqrtf(s), 1e-12f);
    }
    __syncthreads();
    for (int i = tid; i < CCH * 64; i += 256) {
        int c = i >> 6, j = i & 63;
        out[(size_t)(b * CCH + c) * NTOK + t0 + j] = qt[c][j] * sc2[j] * g2s[c];
    }
}

extern "C" void kernel_launch(void* const* d_in, const int* in_sizes, int n_in,
                              void* d_out, int out_size, void* d_ws, size_t ws_size,
                              hipStream_t stream) {
    const float* x    = (const float*)d_in[0];
    const float* g1   = (const float*)d_in[1];
    const float* wqkv = (const float*)d_in[2];
    const float* wout = (const float*)d_in[3];
    const float* bo   = (const float*)d_in[4];
    const float* g2   = (const float*)d_in[5];
    float* out = (float*)d_out;
    char* ws = (char*)d_ws;
    // ws layout (bytes): q_soft bf16 [16][128][16384] @0 (67,108,864)
    //                    pS fp32 [16][32][128]  @67,108,864 (262,144)
    //                    pC fp32 [16][32][4096] @67,371,008 (8,388,608)
    //                    Mg fp32 [16][128][128] @75,759,616 (1,048,576)
    //                    wT fp32 [128][384]     @76,808,192 (196,608)   total ~73.5 MB
    __hip_bfloat16* qs = (__hip_bfloat16*)ws;
    float* pS = (float*)(ws + 67108864);
    float* pC = (float*)(ws + 67371008);
    float* Mg = (float*)(ws + 75759616);
    float* wT = (float*)(ws + 76808192);

    k0_transpose<<<192, 256, 0, stream>>>(wqkv, wT);
    k1_qkv<<<512, 256, 0, stream>>>(x, g1, wT, qs, pS, pC);
    k2_ctx<<<64, 256, 0, stream>>>(pS, pC, wout, Mg);
    k3_out<<<4096, 256, 0, stream>>>(qs, Mg, bo, g2, out);
}

// Round 2
// 336.004 us; speedup vs baseline: 3.8634x; 3.8634x over previous
//
#include <hip/hip_runtime.h>
#include <hip/hip_bf16.h>

#define NTOK 16384
#define SQRT_C 11.313708498984761f
#define QSCALE 0.17677669529663687f

typedef __attribute__((ext_vector_type(8))) short v8s;   // 8 bf16 (4 VGPRs)
typedef __attribute__((ext_vector_type(4))) float v4f;   // 4 fp32 acc

__device__ inline short f2bf(float f) {
    __hip_bfloat16 h = __float2bfloat16(f);
    return __builtin_bit_cast(short, h);
}
__device__ inline float bf2f(short s) {
    unsigned u = ((unsigned)(unsigned short)s) << 16;
    return __builtin_bit_cast(float, u);
}

// ---------------- K0: w_qkv fp32 [384][128] -> bf16 same layout ----------------
__global__ void k0_cvt(const float* __restrict__ wq, short* __restrict__ wbf) {
    int i = blockIdx.x * 256 + threadIdx.x;   // 49152
    wbf[i] = f2bf(wq[i]);
}

// ---------------- K1: rmsnorm + qkv MFMA + softmaxes + ctx MFMA ----------------
// grid 512 = 16 b x 32 chunks of 512 tokens; 256 thr (4 waves); 16 tiles of 32 t.
// Wave w owns qkv output rows 96w..96w+95 and ctx head w.
__global__ __launch_bounds__(256, 2) void k1_qkv(
    const float* __restrict__ x, const float* __restrict__ g1,
    const short* __restrict__ wbf, short* __restrict__ qfrag,
    float* __restrict__ pS, float* __restrict__ pC)
{
    __shared__ float xbuf[128][36];    // x tile [c][t], pad->row 144 B (16-aligned)
    __shared__ short xn[32][136];      // xn bf16 [t][c], row 272 B (16-aligned)
    __shared__ short kvbuf[256][40];   // exp(k) rows 0..127, v rows 128..255; row 80 B
    __shared__ short qbuf[128][33];    // q_soft bf16 [c'][t]
    __shared__ float nrm[8][32];
    __shared__ float scl[32];
    __shared__ float g1s[128];

    const int tid = threadIdx.x;
    const int lane = tid & 63;
    const int w = tid >> 6;
    const int qd = lane >> 4;          // quad 0..3
    const int lm = lane & 15;
    const int b = blockIdx.x >> 5;
    const int chunk = blockIdx.x & 31;
    const size_t xbase = (size_t)b * 128 * NTOK;

    if (tid < 128) g1s[tid] = g1[tid];

    // preload W A-fragments (constant over all tiles): rows 96w..96w+95, K=128
    v8s wA[6][4];
    #pragma unroll
    for (int rg = 0; rg < 6; ++rg)
        #pragma unroll
        for (int kk = 0; kk < 4; ++kk)
            wA[rg][kk] = *(const v8s*)(wbf + (96 * w + rg * 16 + lm) * 128 + kk * 32 + qd * 8);

    v4f cacc[2][2];
    #pragma unroll
    for (int i = 0; i < 2; ++i)
        #pragma unroll
        for (int j = 0; j < 2; ++j)
            cacc[i][j] = (v4f){0.f, 0.f, 0.f, 0.f};
    float accS = 0.f;

    for (int st = 0; st < 16; ++st) {
        const int t0 = chunk * 512 + st * 32;
        __syncthreads();
        // stage x tile [128 c][32 t], coalesced float4
        #pragma unroll
        for (int p = 0; p < 4; ++p) {
            int idx = p * 256 + tid;
            int c = idx >> 3, tq = idx & 7;
            *(float4*)&xbuf[c][tq * 4] =
                *(const float4*)(x + xbase + (size_t)c * NTOK + t0 + tq * 4);
        }
        __syncthreads();
        // per-token sumsq partials
        {
            int t = tid & 31, g = tid >> 5;
            float s = 0.f;
            #pragma unroll
            for (int j = 0; j < 16; ++j) { float v = xbuf[g * 16 + j][t]; s += v * v; }
            nrm[g][t] = s;
        }
        __syncthreads();
        if (tid < 32) {
            float s = 0.f;
            #pragma unroll
            for (int g = 0; g < 8; ++g) s += nrm[g][tid];
            scl[tid] = SQRT_C / fmaxf(sqrtf(s), 1e-12f);
        }
        __syncthreads();
        // xn[t][c] = bf16(x * scale * g1)  (transposed for B-frag reads)
        {
            int t = tid & 31, g = tid >> 5;
            float sc = scl[t];
            #pragma unroll
            for (int j = 0; j < 16; ++j) {
                int c = g * 16 + j;
                xn[t][c] = f2bf(xbuf[c][t] * sc * g1s[c]);
            }
        }
        __syncthreads();
        // qkv MFMA: 96 rows x 32 t per wave, K=128
        v4f C[6][2];
        #pragma unroll
        for (int rg = 0; rg < 6; ++rg) {
            C[rg][0] = (v4f){0.f, 0.f, 0.f, 0.f};
            C[rg][1] = (v4f){0.f, 0.f, 0.f, 0.f};
        }
        #pragma unroll
        for (int kk = 0; kk < 4; ++kk) {
            v8s B0 = *(const v8s*)&xn[lm][kk * 32 + qd * 8];
            v8s B1 = *(const v8s*)&xn[16 + lm][kk * 32 + qd * 8];
            #pragma unroll
            for (int rg = 0; rg < 6; ++rg) {
                C[rg][0] = __builtin_amdgcn_mfma_f32_16x16x32_bf16(wA[rg][kk], B0, C[rg][0], 0, 0, 0);
                C[rg][1] = __builtin_amdgcn_mfma_f32_16x16x32_bf16(wA[rg][kk], B1, C[rg][1], 0, 0, 0);
            }
        }
        // distribute C-frags: q -> in-reg softmax -> qbuf; k -> exp -> kvbuf; v -> kvbuf
        #pragma unroll
        for (int pr = 0; pr < 3; ++pr) {
            const int R = 96 * w + 32 * pr;
            if (R < 128) {                      // q head pair (rows R..R+31, one head's d)
                #pragma unroll
                for (int tg = 0; tg < 2; ++tg) {
                    float e0[4], e1[4];
                    float m = -1e30f;
                    #pragma unroll
                    for (int r = 0; r < 4; ++r) {
                        e0[r] = C[2 * pr][tg][r];
                        e1[r] = C[2 * pr + 1][tg][r];
                        m = fmaxf(m, fmaxf(e0[r], e1[r]));
                    }
                    m = fmaxf(m, __shfl_xor(m, 16, 64));
                    m = fmaxf(m, __shfl_xor(m, 32, 64));
                    float s = 0.f;
                    #pragma unroll
                    for (int r = 0; r < 4; ++r) {
                        e0[r] = __expf(e0[r] - m);
                        e1[r] = __expf(e1[r] - m);
                        s += e0[r] + e1[r];
                    }
                    s += __shfl_xor(s, 16, 64);
                    s += __shfl_xor(s, 32, 64);
                    float inv = QSCALE / s;
                    int col = tg * 16 + lm;
                    #pragma unroll
                    for (int r = 0; r < 4; ++r) {
                        qbuf[R + qd * 4 + r][col]      = f2bf(e0[r] * inv);
                        qbuf[R + 16 + qd * 4 + r][col] = f2bf(e1[r] * inv);
                    }
                }
            } else {                            // k or v rows
                #pragma unroll
                for (int f = 0; f < 2; ++f) {
                    const int rg = 2 * pr + f;
                    const int R2 = R + 16 * f;
                    const bool isk = (R2 < 256);
                    #pragma unroll
                    for (int tg = 0; tg < 2; ++tg) {
                        int col = tg * 16 + lm;
                        #pragma unroll
                        for (int r = 0; r < 4; ++r) {
                            float val = C[rg][tg][r];
                            if (isk) val = __expf(val);
                            kvbuf[R2 - 128 + qd * 4 + r][col] = f2bf(val);
                        }
                    }
                }
            }
        }
        __syncthreads();
        // sum of exp(k) per (h,d) row
        if (tid < 128) {
            const short* row = &kvbuf[tid][0];
            float s = 0.f;
            #pragma unroll
            for (int j = 0; j < 32; ++j) s += bf2f(row[j]);
            accS += s;
        }
        // q gather -> global qfrag in k3 B-frag order (wave w = c-block w)
        {
            const int tb0 = t0 >> 4;
            #pragma unroll
            for (int tbl = 0; tbl < 2; ++tbl) {
                v8s pk;
                #pragma unroll
                for (int j = 0; j < 8; ++j)
                    pk[j] = qbuf[w * 32 + qd * 8 + j][tbl * 16 + lm];
                *(v8s*)(qfrag + ((((size_t)b * 1024 + tb0 + tbl) * 4 + w) << 9) + lane * 8) = pk;
            }
        }
        // context MFMA, head w: ctx[d][e] += sum_t ek[d][t] v[e][t]
        {
            v8s A0 = *(const v8s*)&kvbuf[w * 32 + lm][qd * 8];
            v8s A1 = *(const v8s*)&kvbuf[w * 32 + 16 + lm][qd * 8];
            v8s B0 = *(const v8s*)&kvbuf[128 + w * 32 + lm][qd * 8];
            v8s B1 = *(const v8s*)&kvbuf[128 + w * 32 + 16 + lm][qd * 8];
            cacc[0][0] = __builtin_amdgcn_mfma_f32_16x16x32_bf16(A0, B0, cacc[0][0], 0, 0, 0);
            cacc[0][1] = __builtin_amdgcn_mfma_f32_16x16x32_bf16(A0, B1, cacc[0][1], 0, 0, 0);
            cacc[1][0] = __builtin_amdgcn_mfma_f32_16x16x32_bf16(A1, B0, cacc[1][0], 0, 0, 0);
            cacc[1][1] = __builtin_amdgcn_mfma_f32_16x16x32_bf16(A1, B1, cacc[1][1], 0, 0, 0);
        }
    }
    if (tid < 128) pS[(size_t)(b * 32 + chunk) * 128 + tid] = accS;
    #pragma unroll
    for (int dg = 0; dg < 2; ++dg)
        #pragma unroll
        for (int eg = 0; eg < 2; ++eg)
            #pragma unroll
            for (int r = 0; r < 4; ++r) {
                int d = dg * 16 + qd * 4 + r;
                int e = eg * 16 + lm;
                pC[(size_t)(b * 32 + chunk) * 4096 + w * 1024 + d * 32 + e] = cacc[dg][eg][r];
            }
}

// ---------------- K2: reduce partials -> ctx -> MgT bf16 [b][o][c'] -------------
__global__ void k2_ctx(const float* __restrict__ pS, const float* __restrict__ pC,
                       const float* __restrict__ wout, short* __restrict__ MgT) {
    __shared__ float ctx[32][33];
    __shared__ float Sv[32];
    const int tid = threadIdx.x;
    const int b = blockIdx.x >> 2, h = blockIdx.x & 3;
    if (tid < 32) {
        float s = 0.f;
        for (int ch = 0; ch < 32; ++ch) s += pS[(size_t)(b * 32 + ch) * 128 + h * 32 + tid];
        Sv[tid] = s;
    }
    __syncthreads();
    #pragma unroll
    for (int k = 0; k < 4; ++k) {
        int de = tid + k * 256;
        float s = 0.f;
        for (int ch = 0; ch < 32; ++ch) s += pC[(size_t)(b * 32 + ch) * 4096 + h * 1024 + de];
        ctx[de >> 5][de & 31] = s / Sv[de >> 5];
    }
    __syncthreads();
    // M[h*32+d][o] = sum_e wout[o][h*32+e] * ctx[d][e]; store transposed bf16 at [o][h*32+d]
    #pragma unroll
    for (int k = 0; k < 16; ++k) {
        int idx = tid + k * 256;
        int d = idx & 31, o = idx >> 5;
        float m = 0.f;
        #pragma unroll
        for (int e = 0; e < 32; ++e) m += wout[o * 128 + h * 32 + e] * ctx[d][e];
        MgT[((size_t)b * 128 + o) * 128 + h * 32 + d] = f2bf(m);
    }
}

// ---------------- K3: y = M_b @ q_soft + b_out -> rmsnorm(g2) (MFMA) ------------
// grid 2048 = 16 b x 128 chunks of 128 tokens; wave w owns rows 32w..32w+31
__global__ __launch_bounds__(256) void k3_out(
    const short* __restrict__ qfrag, const short* __restrict__ MgT,
    const float* __restrict__ bo, const float* __restrict__ g2,
    float* __restrict__ out)
{
    __shared__ float part[4][128];
    __shared__ float scl[128];
    const int tid = threadIdx.x;
    const int lane = tid & 63, w = tid >> 6;
    const int qd = lane >> 4, lm = lane & 15;
    const int b = blockIdx.x >> 7;
    const int t0 = (blockIdx.x & 127) << 7;
    const int tb0 = t0 >> 4;

    v8s A[2][4];
    #pragma unroll
    for (int rg = 0; rg < 2; ++rg)
        #pragma unroll
        for (int kk = 0; kk < 4; ++kk)
            A[rg][kk] = *(const v8s*)(MgT + ((size_t)b * 128 + 32 * w + rg * 16 + lm) * 128 + kk * 32 + qd * 8);

    v4f C[2][8];
    #pragma unroll
    for (int rg = 0; rg < 2; ++rg)
        #pragma unroll
        for (int tb = 0; tb < 8; ++tb)
            C[rg][tb] = (v4f){0.f, 0.f, 0.f, 0.f};

    #pragma unroll
    for (int tb = 0; tb < 8; ++tb)
        #pragma unroll
        for (int kk = 0; kk < 4; ++kk) {
            v8s B = *(const v8s*)(qfrag + ((((size_t)b * 1024 + tb0 + tb) * 4 + kk) << 9) + lane * 8);
            C[0][tb] = __builtin_amdgcn_mfma_f32_16x16x32_bf16(A[0][kk], B, C[0][tb], 0, 0, 0);
            C[1][tb] = __builtin_amdgcn_mfma_f32_16x16x32_bf16(A[1][kk], B, C[1][tb], 0, 0, 0);
        }

    float bov[2][4], g2v[2][4];
    #pragma unroll
    for (int rg = 0; rg < 2; ++rg)
        #pragma unroll
        for (int r = 0; r < 4; ++r) {
            int o = 32 * w + rg * 16 + qd * 4 + r;
            bov[rg][r] = bo[o];
            g2v[rg][r] = g2[o];
        }
    // bias + per-token sumsq (reduce 32 rows via xor shuffles, cross-wave via LDS)
    #pragma unroll
    for (int tb = 0; tb < 8; ++tb) {
        float ss = 0.f;
        #pragma unroll
        for (int rg = 0; rg < 2; ++rg)
            #pragma unroll
            for (int r = 0; r < 4; ++r) {
                C[rg][tb][r] += bov[rg][r];
                ss += C[rg][tb][r] * C[rg][tb][r];
            }
        ss += __shfl_xor(ss, 16, 64);
        ss += __shfl_xor(ss, 32, 64);
        if (lane < 16) part[w][tb * 16 + lane] = ss;
    }
    __syncthreads();
    if (tid < 128) {
        float s = part[0][tid] + part[1][tid] + part[2][tid] + part[3][tid];
        scl[tid] = SQRT_C / fmaxf(sqrtf(s), 1e-12f);
    }
    __syncthreads();
    #pragma unroll
    for (int tb = 0; tb < 8; ++tb) {
        float sc = scl[tb * 16 + lm];
        #pragma unroll
        for (int rg = 0; rg < 2; ++rg)
            #pragma unroll
            for (int r = 0; r < 4; ++r) {
                int o = 32 * w + rg * 16 + qd * 4 + r;
                out[((size_t)b * 128 + o) * NTOK + t0 + tb * 16 + lm] = C[rg][tb][r] * sc * g2v[rg][r];
            }
    }
}

extern "C" void kernel_launch(void* const* d_in, const int* in_sizes, int n_in,
                              void* d_out, int out_size, void* d_ws, size_t ws_size,
                              hipStream_t stream) {
    const float* x    = (const float*)d_in[0];
    const float* g1   = (const float*)d_in[1];
    const float* wqkv = (const float*)d_in[2];
    const float* wout = (const float*)d_in[3];
    const float* bo   = (const float*)d_in[4];
    const float* g2   = (const float*)d_in[5];
    float* out = (float*)d_out;
    char* ws = (char*)d_ws;
    // ws: qfrag bf16 [16][1024][4][512] @0 (67,108,864 B)
    //     pS fp32 [16][32][128]  @67,108,864 (262,144)
    //     pC fp32 [16][32][4096] @67,371,008 (8,388,608)
    //     MgT bf16 [16][128][128] @75,759,616 (524,288)
    //     wbf bf16 [384][128]     @76,283,904 (98,304)   total 76,382,208 B
    short* qfrag = (short*)ws;
    float* pS = (float*)(ws + 67108864);
    float* pC = (float*)(ws + 67371008);
    short* MgT = (short*)(ws + 75759616);
    short* wbf = (short*)(ws + 76283904);

    k0_cvt<<<192, 256, 0, stream>>>(wqkv, wbf);
    k1_qkv<<<512, 256, 0, stream>>>(x, g1, wbf, qfrag, pS, pC);
    k2_ctx<<<64, 256, 0, stream>>>(pS, pC, wout, MgT);
    k3_out<<<2048, 256, 0, stream>>>(qfrag, MgT, bo, g2, out);
}